// Round 3
// baseline (1261.841 us; speedup 1.0000x reference)
//
#include <hip/hip_runtime.h>
#include <hip/hip_bf16.h>
#include <cstdint>
#include <cstddef>

#define BDIM 256

// ---- storage conversion helpers (compute is always f32) --------------------
__device__ __forceinline__ float ldf(const float* p) { return *p; }
__device__ __forceinline__ float ldf(const __hip_bfloat16* p) { return __bfloat162float(*p); }
__device__ __forceinline__ void stf(float* p, float v) { *p = v; }
__device__ __forceinline__ void stf(__hip_bfloat16* p, float v) { *p = __float2bfloat16(v); }

// ---------------------------------------------------------------------------
// 3x3 SAME conv, NCHW, square image of side (1<<LW). One thread = one output
// pixel, all COUT channels accumulated in registers. Weight/bias indices are
// wave-uniform -> scalar loads through the constant cache.
// ---------------------------------------------------------------------------
template<int CIN, int COUT, bool RELU, int LW, typename TI, typename TO>
__global__ __launch_bounds__(BDIM) void conv3x3_k(
    const TI* __restrict__ in, const float* __restrict__ wq,
    const float* __restrict__ bias, TO* __restrict__ out)
{
    constexpr int Wd = 1 << LW;
    constexpr int PLANE = Wd * Wd;
    const int pix = blockIdx.x * BDIM + threadIdx.x;
    const int n = blockIdx.y;
    const int y = pix >> LW;
    const int x = pix & (Wd - 1);

    const TI* inp = in + (size_t)n * CIN * PLANE + pix;

    float acc[COUT];
    #pragma unroll
    for (int co = 0; co < COUT; ++co) acc[co] = bias[co];

    #pragma unroll 1
    for (int ci = 0; ci < CIN; ++ci) {
        const TI* p = inp + (size_t)ci * PLANE;
        float v[9];
        #pragma unroll
        for (int ky = 0; ky < 3; ++ky) {
            const int yy = y + ky - 1;
            const bool yok = (unsigned)yy < (unsigned)Wd;
            #pragma unroll
            for (int kx = 0; kx < 3; ++kx) {
                const int xx = x + kx - 1;
                const bool ok = yok && ((unsigned)xx < (unsigned)Wd);
                v[ky * 3 + kx] = ok ? ldf(p + (ky - 1) * Wd + (kx - 1)) : 0.0f;
            }
        }
        const float* wci = wq + ci * 9;
        #pragma unroll
        for (int co = 0; co < COUT; ++co) {
            const float* wc = wci + co * CIN * 9;
            float s = acc[co];
            #pragma unroll
            for (int k = 0; k < 9; ++k) s = fmaf(wc[k], v[k], s);
            acc[co] = s;
        }
    }

    TO* op = out + (size_t)n * COUT * PLANE + pix;
    #pragma unroll
    for (int co = 0; co < COUT; ++co) {
        float r = acc[co];
        if (RELU) r = fmaxf(r, 0.0f);
        stf(op + (size_t)co * PLANE, r);
    }
}

// ---------------------------------------------------------------------------
// 2x2 maxpool, (4,32,512,512) -> (4,32,256,256), one thread per output elem.
// ---------------------------------------------------------------------------
template<typename TI, typename TO>
__global__ __launch_bounds__(BDIM) void maxpool_k(
    const TI* __restrict__ in, TO* __restrict__ out)
{
    const int idx = blockIdx.x * BDIM + threadIdx.x;     // 4*32*256*256 total
    const int x = idx & 255;
    const int y = (idx >> 8) & 255;
    const int p = idx >> 16;                              // plane = n*32+c
    const TI* ip = in + ((size_t)p * 512 + 2 * y) * 512 + 2 * x;
    const float m = fmaxf(fmaxf(ldf(ip), ldf(ip + 1)),
                          fmaxf(ldf(ip + 512), ldf(ip + 513)));
    stf(out + idx, m);
}

// ---------------------------------------------------------------------------
// ConvTranspose 2x2 stride 2 + skip add, IN-PLACE over du (which holds d).
// u[n,co,2i+a,2j+b] = d[..] + bt[co] + sum_ci e[n,ci,i,j]*wt[ci,co,a,b]
// One thread per low-res pixel (i,j); writes the 2x2 output quad for all co.
// ---------------------------------------------------------------------------
template<typename TE, typename TD>
__global__ __launch_bounds__(BDIM) void convT_add_k(
    const TE* __restrict__ e, const float* __restrict__ wt,
    const float* __restrict__ bt, TD* __restrict__ du)
{
    const int pix = blockIdx.x * BDIM + threadIdx.x;     // 65536 per image
    const int n = blockIdx.y;
    const int i = pix >> 8;
    const int j = pix & 255;

    const TE* ep = e + (size_t)n * 32 * 65536 + pix;
    float ev[32];
    #pragma unroll
    for (int ci = 0; ci < 32; ++ci) ev[ci] = ldf(ep + (size_t)ci * 65536);

    TD* dp = du + (size_t)n * 32 * 262144 + (size_t)(2 * i) * 512 + 2 * j;
    const float4* wt4 = (const float4*)wt;               // wt[ci][co][2][2]

    #pragma unroll 1
    for (int co = 0; co < 32; ++co) {
        const float b = bt[co];
        float a0 = b, a1 = b, a2 = b, a3 = b;
        #pragma unroll
        for (int ci = 0; ci < 32; ++ci) {
            const float4 wv = wt4[ci * 32 + co];
            const float v = ev[ci];
            a0 = fmaf(v, wv.x, a0); a1 = fmaf(v, wv.y, a1);
            a2 = fmaf(v, wv.z, a2); a3 = fmaf(v, wv.w, a3);
        }
        TD* o = dp + (size_t)co * 262144;
        stf(o,       ldf(o)       + a0);
        stf(o + 1,   ldf(o + 1)   + a1);
        stf(o + 512, ldf(o + 512) + a2);
        stf(o + 513, ldf(o + 513) + a3);
    }
}

// ---------------------------------------------------------------------------
// Bilateral filter. combined = concat(x[:, :11], feats[16]) (never
// materialized). 5x5 taps, dilation 2, zero-mask outside -> OOB taps skipped.
// Only first 11 channels of num are emitted; center tap guarantees den>=~1.
// ---------------------------------------------------------------------------
template<typename TF>
__global__ __launch_bounds__(BDIM) void bilateral_k(
    const float* __restrict__ xin, const TF* __restrict__ feats,
    const float* __restrict__ fp, float* __restrict__ out)
{
    const int pix = blockIdx.x * BDIM + threadIdx.x;     // 262144 per image
    const int n = blockIdx.y;
    const int y = pix >> 9;
    const int x = pix & 511;
    constexpr int PLANE = 512 * 512;

    float cw[27];
    #pragma unroll
    for (int i = 0; i < 27; ++i) cw[i] = fp[i];
    const float sy = fp[27];
    const float sx = fp[28];

    const float* xb = xin   + (size_t)n * 16 * PLANE + pix;   // x has 16 ch, use 11
    const TF*    fb = feats + (size_t)n * 16 * PLANE + pix;

    float c[27];
    #pragma unroll
    for (int i = 0; i < 11; ++i) c[i]      = xb[(size_t)i * PLANE];
    #pragma unroll
    for (int i = 0; i < 16; ++i) c[11 + i] = ldf(fb + (size_t)i * PLANE);

    float num[11];
    #pragma unroll
    for (int i = 0; i < 11; ++i) num[i] = 0.0f;
    float den = 0.0f;

    for (int dy = -2; dy <= 2; ++dy) {
        const int oy = 2 * dy;
        const int yy = y + oy;
        if ((unsigned)yy >= 512u) continue;
        for (int dx = -2; dx <= 2; ++dx) {
            const int ox = 2 * dx;
            const int xx = x + ox;
            if ((unsigned)xx >= 512u) continue;

            const int off = oy * 512 + ox;
            float logw = sy * (float)(oy * oy) + sx * (float)(ox * ox);

            float shv[11];
            #pragma unroll
            for (int i = 0; i < 11; ++i) {
                const float s = xb[(size_t)i * PLANE + off];
                shv[i] = s;
                const float d = s - c[i];
                logw = fmaf(cw[i], d * d, logw);
            }
            #pragma unroll
            for (int i = 0; i < 16; ++i) {
                const float s = ldf(fb + (size_t)i * PLANE + off);
                const float d = s - c[11 + i];
                logw = fmaf(cw[11 + i], d * d, logw);
            }
            const float w = __expf(logw);
            #pragma unroll
            for (int i = 0; i < 11; ++i) num[i] = fmaf(w, shv[i], num[i]);
            den += w;
        }
    }

    const float inv = 1.0f / den;
    float* ob = out + (size_t)n * 11 * PLANE + pix;
    #pragma unroll
    for (int i = 0; i < 11; ++i) ob[(size_t)i * PLANE] = num[i] * inv;
}

// ---------------------------------------------------------------------------
// Whole pipeline for a given storage-type triple (SD=d/u, SA=bufA/e, SB=bufB/e)
// ---------------------------------------------------------------------------
template<typename SD, typename SA, typename SB>
static void run_pipeline(const float* x, const float* const* Wv, const float* const* Bv,
                         const float* wt, const float* bt, const float* fp,
                         float* out, SD* du, SA* bufA, SB* bufB, hipStream_t stream)
{
    const dim3 blk(BDIM);
    const dim3 g512(512 * 512 / BDIM, 4);   // (1024,4)
    const dim3 g256(256 * 256 / BDIM, 4);   // (256,4)

    // encoder head: d = conv2(relu(conv1(relu(conv0(x)))))
    conv3x3_k<16, 16, true,  9><<<g512, blk, 0, stream>>>(x,    Wv[0], Bv[0], bufA);
    conv3x3_k<16, 16, true,  9><<<g512, blk, 0, stream>>>(bufA, Wv[1], Bv[1], bufB);
    conv3x3_k<16, 32, false, 9><<<g512, blk, 0, stream>>>(bufB, Wv[2], Bv[2], du);

    // e = maxpool(d); 3x (relu conv 32->32) at 256^2, ping-pong in bufA/bufB
    maxpool_k<<<dim3(4 * 32 * 256 * 256 / BDIM), blk, 0, stream>>>(du, bufA);
    conv3x3_k<32, 32, true, 8><<<g256, blk, 0, stream>>>(bufA, Wv[3], Bv[3], bufB);
    conv3x3_k<32, 32, true, 8><<<g256, blk, 0, stream>>>(bufB, Wv[4], Bv[4], bufA);
    conv3x3_k<32, 32, true, 8><<<g256, blk, 0, stream>>>(bufA, Wv[5], Bv[5], bufB);

    // u = convT(e) + d   (in place over du)
    convT_add_k<<<g256, blk, 0, stream>>>(bufB, wt, bt, du);

    // feats = conv8(relu(conv7(relu(conv6(u)))))
    conv3x3_k<32, 16, true,  9><<<g512, blk, 0, stream>>>(du,   Wv[6], Bv[6], bufA);
    conv3x3_k<16, 16, true,  9><<<g512, blk, 0, stream>>>(bufA, Wv[7], Bv[7], bufB);
    conv3x3_k<16, 16, false, 9><<<g512, blk, 0, stream>>>(bufB, Wv[8], Bv[8], bufA);

    // bilateral over concat(x[:, :11], feats), emit 11 channels
    bilateral_k<<<g512, blk, 0, stream>>>(x, bufA, fp, out);
}

// ---------------------------------------------------------------------------
extern "C" void kernel_launch(void* const* d_in, const int* in_sizes, int n_in,
                              void* d_out, int out_size, void* d_ws, size_t ws_size,
                              hipStream_t stream)
{
    const float* x = (const float*)d_in[0];
    const float* Wv[9];
    const float* Bv[9];
    if (in_sizes[2] == 16) {
        // dict order: x, w0, b0, w1, b1, ..., w8, b8, wt, bt, fparams
        for (int i = 0; i < 9; ++i) {
            Wv[i] = (const float*)d_in[1 + 2 * i];
            Bv[i] = (const float*)d_in[2 + 2 * i];
        }
    } else {
        // signature order fallback: x, w0..w8, b0..b8, wt, bt, fparams
        for (int i = 0; i < 9; ++i) {
            Wv[i] = (const float*)d_in[1 + i];
            Bv[i] = (const float*)d_in[10 + i];
        }
    }
    const float* wt = (const float*)d_in[19];
    const float* bt = (const float*)d_in[20];
    const float* fp = (const float*)d_in[21];
    float* out = (float*)d_out;

    char* ws = (char*)d_ws;
    constexpr size_t MiB = 1ull << 20;

    if (ws_size >= 256 * MiB) {
        // all f32: du 128MiB @0, bufA 64MiB @128, bufB 64MiB @192
        run_pipeline<float, float, float>(
            x, Wv, Bv, wt, bt, fp, out,
            (float*)ws, (float*)(ws + 128 * MiB), (float*)(ws + 192 * MiB), stream);
    } else if (ws_size >= 192 * MiB) {
        // du f32 128MiB @0, bufA/bufB bf16 32MiB @128/@160
        run_pipeline<float, __hip_bfloat16, __hip_bfloat16>(
            x, Wv, Bv, wt, bt, fp, out,
            (float*)ws, (__hip_bfloat16*)(ws + 128 * MiB),
            (__hip_bfloat16*)(ws + 160 * MiB), stream);
    } else if (ws_size >= 128 * MiB) {
        // all bf16: du 64MiB @0, bufA 32MiB @64, bufB 32MiB @96
        run_pipeline<__hip_bfloat16, __hip_bfloat16, __hip_bfloat16>(
            x, Wv, Bv, wt, bt, fp, out,
            (__hip_bfloat16*)ws, (__hip_bfloat16*)(ws + 64 * MiB),
            (__hip_bfloat16*)(ws + 96 * MiB), stream);
    } else {
        // last resort (ws >= 96MiB): bufB lives in d_out (44MB >= 32MiB needed;
        // dead before bilateral's final write)
        run_pipeline<__hip_bfloat16, __hip_bfloat16, __hip_bfloat16>(
            x, Wv, Bv, wt, bt, fp, out,
            (__hip_bfloat16*)ws, (__hip_bfloat16*)(ws + 64 * MiB),
            (__hip_bfloat16*)d_out, stream);
    }

    (void)n_in; (void)out_size; (void)ws_size;
}

// Round 4
// 1087.083 us; speedup vs baseline: 1.1608x; 1.1608x over previous
//
#include <hip/hip_runtime.h>
#include <hip/hip_bf16.h>
#include <cstdint>
#include <cstddef>

#define BDIM 256
typedef __hip_bfloat16 bf16;

// ---- bf16 bit helpers (exact up-convert, RNE down-convert) -----------------
__device__ __forceinline__ float bfu2f(unsigned short u) {
    unsigned int w = (unsigned int)u << 16;
    float f; __builtin_memcpy(&f, &w, 4); return f;
}
__device__ __forceinline__ unsigned short f2bfu(float f) {
    bf16 h = __float2bfloat16(f);
    unsigned short u; __builtin_memcpy(&u, &h, 2); return u;
}
__device__ __forceinline__ float ldf(const float* p) { return *p; }
__device__ __forceinline__ float ldf(const bf16* p) {
    unsigned short u; __builtin_memcpy(&u, p, 2); return bfu2f(u);
}

// vector load of 4 consecutive (8B-aligned for bf16, 16B for f32)
__device__ __forceinline__ void ld4(const float* p, float& a, float& b, float& c, float& d) {
    const float4 t = *reinterpret_cast<const float4*>(p);
    a = t.x; b = t.y; c = t.z; d = t.w;
}
__device__ __forceinline__ void ld4(const bf16* p, float& a, float& b, float& c, float& d) {
    const ushort4 t = *reinterpret_cast<const ushort4*>(p);
    a = bfu2f(t.x); b = bfu2f(t.y); c = bfu2f(t.z); d = bfu2f(t.w);
}
__device__ __forceinline__ void st4(float* p, float a, float b, float c, float d) {
    float4 t; t.x = a; t.y = b; t.z = c; t.w = d;
    *reinterpret_cast<float4*>(p) = t;
}
__device__ __forceinline__ void st4(bf16* p, float a, float b, float c, float d) {
    ushort4 t; t.x = f2bfu(a); t.y = f2bfu(b); t.z = f2bfu(c); t.w = f2bfu(d);
    *reinterpret_cast<ushort4*>(p) = t;
}

// ---------------------------------------------------------------------------
// 3x3 SAME conv, NCHW, side (1<<LW). One thread = 4 consecutive x pixels,
// 16 output channels in registers (acc[16][4]). Weights are wave-uniform ->
// scalar loads; 576 FMA per ci-iter vs 144 s_loads (1:4).
// COUT_N = total output channels (n-stride); host pre-offsets wq/bias/out
// for co-tiles of 16.
// ---------------------------------------------------------------------------
template<int CIN, int COUT_N, bool RELU, int LW, typename TI, typename TO>
__global__ __launch_bounds__(BDIM) void conv4_k(
    const TI* __restrict__ in, const float* __restrict__ wq,
    const float* __restrict__ bias, TO* __restrict__ out)
{
    constexpr int Wd = 1 << LW;
    constexpr int PLANE = Wd * Wd;
    constexpr int TPR = Wd >> 2;                 // threads per row
    const int t = blockIdx.x * BDIM + threadIdx.x;
    const int n = blockIdx.y;
    const int y = t >> (LW - 2);
    const int x4 = (t & (TPR - 1)) << 2;

    const TI* inp = in + (size_t)n * CIN * PLANE + (size_t)y * Wd + x4;

    float acc[16][4];
    #pragma unroll
    for (int co = 0; co < 16; ++co) {
        const float b = bias[co];
        acc[co][0] = b; acc[co][1] = b; acc[co][2] = b; acc[co][3] = b;
    }

    const bool xl = (x4 > 0);
    const bool xr = (x4 + 4 < Wd);
    const int li = xl ? -1 : 0;                  // clamped (in-bounds) indices
    const int ri = xr ? 4 : 3;

    #pragma unroll 1
    for (int ci = 0; ci < CIN; ++ci) {
        const TI* p = inp + (size_t)ci * PLANE;
        float v[3][6];
        #pragma unroll
        for (int r = 0; r < 3; ++r) {
            const int yy = y + r - 1;            // wave-uniform branch
            if ((unsigned)yy < (unsigned)Wd) {
                const TI* q = p + (r - 1) * Wd;
                ld4(q, v[r][1], v[r][2], v[r][3], v[r][4]);
                const float lv = ldf(q + li);
                const float rv = ldf(q + ri);
                v[r][0] = xl ? lv : 0.0f;
                v[r][5] = xr ? rv : 0.0f;
            } else {
                #pragma unroll
                for (int i = 0; i < 6; ++i) v[r][i] = 0.0f;
            }
        }
        const float* wci = wq + ci * 9;
        #pragma unroll
        for (int co = 0; co < 16; ++co) {
            const float* w = wci + co * CIN * 9;
            #pragma unroll
            for (int ky = 0; ky < 3; ++ky) {
                #pragma unroll
                for (int kx = 0; kx < 3; ++kx) {
                    const float wv = w[ky * 3 + kx];
                    acc[co][0] = fmaf(wv, v[ky][kx + 0], acc[co][0]);
                    acc[co][1] = fmaf(wv, v[ky][kx + 1], acc[co][1]);
                    acc[co][2] = fmaf(wv, v[ky][kx + 2], acc[co][2]);
                    acc[co][3] = fmaf(wv, v[ky][kx + 3], acc[co][3]);
                }
            }
        }
    }

    TO* op = out + (size_t)n * COUT_N * PLANE + (size_t)y * Wd + x4;
    #pragma unroll
    for (int co = 0; co < 16; ++co) {
        float a0 = acc[co][0], a1 = acc[co][1], a2 = acc[co][2], a3 = acc[co][3];
        if (RELU) {
            a0 = fmaxf(a0, 0.f); a1 = fmaxf(a1, 0.f);
            a2 = fmaxf(a2, 0.f); a3 = fmaxf(a3, 0.f);
        }
        st4(op + (size_t)co * PLANE, a0, a1, a2, a3);
    }
}

// ---------------------------------------------------------------------------
// 2x2 maxpool, bf16 (4,32,512,512) -> (4,32,256,256), 1 thread/out elem.
// ---------------------------------------------------------------------------
__global__ __launch_bounds__(BDIM) void maxpool_k(
    const bf16* __restrict__ in, bf16* __restrict__ out)
{
    const int idx = blockIdx.x * BDIM + threadIdx.x;   // 4*32*256*256
    const int x = idx & 255;
    const int y = (idx >> 8) & 255;
    const int p = idx >> 16;
    const bf16* ip = in + ((size_t)p * 512 + 2 * y) * 512 + 2 * x;
    const ushort2 a = *reinterpret_cast<const ushort2*>(ip);
    const ushort2 b = *reinterpret_cast<const ushort2*>(ip + 512);
    const float m = fmaxf(fmaxf(bfu2f(a.x), bfu2f(a.y)),
                          fmaxf(bfu2f(b.x), bfu2f(b.y)));
    unsigned short r = f2bfu(m);
    __builtin_memcpy(out + idx, &r, 2);
}

// ---------------------------------------------------------------------------
// ConvTranspose 2x2 stride 2 + skip add, IN-PLACE over du (bf16).
// ---------------------------------------------------------------------------
__global__ __launch_bounds__(BDIM) void convT_add_k(
    const bf16* __restrict__ e, const float* __restrict__ wt,
    const float* __restrict__ bt, bf16* __restrict__ du)
{
    const int pix = blockIdx.x * BDIM + threadIdx.x;   // 65536 per image
    const int n = blockIdx.y;
    const int i = pix >> 8;
    const int j = pix & 255;

    const bf16* ep = e + (size_t)n * 32 * 65536 + pix;
    float ev[32];
    #pragma unroll
    for (int ci = 0; ci < 32; ++ci) ev[ci] = ldf(ep + (size_t)ci * 65536);

    bf16* dp = du + (size_t)n * 32 * 262144 + (size_t)(2 * i) * 512 + 2 * j;
    const float4* wt4 = (const float4*)wt;             // wt[ci][co][2][2]

    #pragma unroll 1
    for (int co = 0; co < 32; ++co) {
        const float b = bt[co];
        float a0 = b, a1 = b, a2 = b, a3 = b;
        #pragma unroll
        for (int ci = 0; ci < 32; ++ci) {
            const float4 wv = wt4[ci * 32 + co];
            const float v = ev[ci];
            a0 = fmaf(v, wv.x, a0); a1 = fmaf(v, wv.y, a1);
            a2 = fmaf(v, wv.z, a2); a3 = fmaf(v, wv.w, a3);
        }
        bf16* o = dp + (size_t)co * 262144;
        ushort2* o0 = reinterpret_cast<ushort2*>(o);
        ushort2* o1 = reinterpret_cast<ushort2*>(o + 512);
        const ushort2 u0 = *o0, u1 = *o1;
        ushort2 r0, r1;
        r0.x = f2bfu(bfu2f(u0.x) + a0); r0.y = f2bfu(bfu2f(u0.y) + a1);
        r1.x = f2bfu(bfu2f(u1.x) + a2); r1.y = f2bfu(bfu2f(u1.y) + a3);
        *o0 = r0; *o1 = r1;
    }
}

// ---------------------------------------------------------------------------
// Bilateral, 2 px/thread. combined = concat(x[:, :11] f32, feats[16] bf16).
// All tap offsets are even and x is even => the px pair is valid/invalid
// together (single mask, vector loads stay in-bounds when valid).
// ---------------------------------------------------------------------------
__global__ __launch_bounds__(BDIM) void bilateral2_k(
    const float* __restrict__ xin, const bf16* __restrict__ feats,
    const float* __restrict__ fp, float* __restrict__ out)
{
    constexpr int PLANE = 512 * 512;
    const int t = blockIdx.x * BDIM + threadIdx.x;     // 131072 per image
    const int n = blockIdx.y;
    const int y = t >> 8;
    const int x = (t & 255) << 1;

    float cw[27];
    #pragma unroll
    for (int i = 0; i < 27; ++i) cw[i] = fp[i];
    const float sy = fp[27], sx = fp[28];

    const float* xb = xin   + (size_t)n * 16 * PLANE + (size_t)y * 512 + x;
    const bf16*  fb = feats + (size_t)n * 16 * PLANE + (size_t)y * 512 + x;

    float c[27][2];
    #pragma unroll
    for (int i = 0; i < 11; ++i) {
        const float2 s = *reinterpret_cast<const float2*>(xb + (size_t)i * PLANE);
        c[i][0] = s.x; c[i][1] = s.y;
    }
    #pragma unroll
    for (int i = 0; i < 16; ++i) {
        const ushort2 u = *reinterpret_cast<const ushort2*>(fb + (size_t)i * PLANE);
        c[11 + i][0] = bfu2f(u.x); c[11 + i][1] = bfu2f(u.y);
    }

    float num[11][2];
    #pragma unroll
    for (int i = 0; i < 11; ++i) { num[i][0] = 0.f; num[i][1] = 0.f; }
    float den0 = 0.f, den1 = 0.f;

    #pragma unroll 1
    for (int dy = -2; dy <= 2; ++dy) {
        const int yy = y + 2 * dy;
        if ((unsigned)yy > 511u) continue;             // block-uniform
        const float by = sy * (float)(4 * dy * dy);
        #pragma unroll
        for (int dx = -2; dx <= 2; ++dx) {
            const int xx = x + 2 * dx;
            if ((unsigned)xx > 510u) continue;         // edge lanes only
            const int off = dy * 1024 + dx * 2;
            float l0 = fmaf(sx, (float)(4 * dx * dx), by);
            float l1 = l0;
            float shv[11][2];
            #pragma unroll
            for (int i = 0; i < 11; ++i) {
                const float2 s = *reinterpret_cast<const float2*>(xb + (size_t)i * PLANE + off);
                shv[i][0] = s.x; shv[i][1] = s.y;
                const float d0 = s.x - c[i][0];
                const float d1 = s.y - c[i][1];
                l0 = fmaf(cw[i], d0 * d0, l0);
                l1 = fmaf(cw[i], d1 * d1, l1);
            }
            #pragma unroll
            for (int i = 0; i < 16; ++i) {
                const ushort2 u = *reinterpret_cast<const ushort2*>(fb + (size_t)i * PLANE + off);
                const float d0 = bfu2f(u.x) - c[11 + i][0];
                const float d1 = bfu2f(u.y) - c[11 + i][1];
                l0 = fmaf(cw[11 + i], d0 * d0, l0);
                l1 = fmaf(cw[11 + i], d1 * d1, l1);
            }
            const float w0 = __expf(l0), w1 = __expf(l1);
            #pragma unroll
            for (int i = 0; i < 11; ++i) {
                num[i][0] = fmaf(w0, shv[i][0], num[i][0]);
                num[i][1] = fmaf(w1, shv[i][1], num[i][1]);
            }
            den0 += w0; den1 += w1;
        }
    }

    const float i0 = 1.f / den0, i1 = 1.f / den1;
    float* ob = out + (size_t)n * 11 * PLANE + (size_t)y * 512 + x;
    #pragma unroll
    for (int i = 0; i < 11; ++i) {
        float2 r; r.x = num[i][0] * i0; r.y = num[i][1] * i1;
        *reinterpret_cast<float2*>(ob + (size_t)i * PLANE) = r;
    }
}

// ---------------------------------------------------------------------------
extern "C" void kernel_launch(void* const* d_in, const int* in_sizes, int n_in,
                              void* d_out, int out_size, void* d_ws, size_t ws_size,
                              hipStream_t stream)
{
    const float* x = (const float*)d_in[0];
    const float* Wv[9];
    const float* Bv[9];
    if (in_sizes[2] == 16) {
        for (int i = 0; i < 9; ++i) {            // dict order: x,w0,b0,w1,b1,...
            Wv[i] = (const float*)d_in[1 + 2 * i];
            Bv[i] = (const float*)d_in[2 + 2 * i];
        }
    } else {
        for (int i = 0; i < 9; ++i) {            // signature order fallback
            Wv[i] = (const float*)d_in[1 + i];
            Bv[i] = (const float*)d_in[10 + i];
        }
    }
    const float* wt = (const float*)d_in[19];
    const float* bt = (const float*)d_in[20];
    const float* fp = (const float*)d_in[21];
    float* out = (float*)d_out;

    constexpr size_t MiB = 1ull << 20;
    constexpr int P512 = 512 * 512;
    char* ws = (char*)d_ws;
    bf16* du   = (bf16*)ws;                      // 4*32*512^2*2 = 64 MiB
    bf16* bufA = (bf16*)(ws + 64 * MiB);         // 32 MiB
    bf16* bufB;
    if (ws_size >= 128 * MiB) bufB = (bf16*)(ws + 96 * MiB);
    else                      bufB = (bf16*)d_out;   // 32 MiB, dead before final write

    const dim3 blk(BDIM);
    const dim3 c512(P512 / 4 / BDIM, 4);         // (256,4)  conv 4px/thread @512^2
    const dim3 c256(256 * 256 / 4 / BDIM, 4);    // (64,4)   conv 4px/thread @256^2
    const dim3 b512(P512 / 2 / BDIM, 4);         // (512,4)  bilateral 2px/thread

    // encoder head: d = conv2(relu(conv1(relu(conv0(x)))))
    conv4_k<16, 16, true,  9, float, bf16><<<c512, blk, 0, stream>>>(x,    Wv[0], Bv[0], bufA);
    conv4_k<16, 16, true,  9, bf16,  bf16><<<c512, blk, 0, stream>>>(bufA, Wv[1], Bv[1], bufB);
    conv4_k<16, 32, false, 9, bf16,  bf16><<<c512, blk, 0, stream>>>(bufB, Wv[2], Bv[2], du);
    conv4_k<16, 32, false, 9, bf16,  bf16><<<c512, blk, 0, stream>>>(bufB, Wv[2] + 16 * 16 * 9, Bv[2] + 16, du + (size_t)16 * P512);

    // e = maxpool(d); 3x (relu conv 32->32) @256^2, ping-pong bufA/bufB
    maxpool_k<<<dim3(4 * 32 * 256 * 256 / BDIM), blk, 0, stream>>>(du, bufA);
    constexpr int P256 = 256 * 256;
    constexpr int WOFF = 16 * 32 * 9;
    conv4_k<32, 32, true, 8, bf16, bf16><<<c256, blk, 0, stream>>>(bufA, Wv[3], Bv[3], bufB);
    conv4_k<32, 32, true, 8, bf16, bf16><<<c256, blk, 0, stream>>>(bufA, Wv[3] + WOFF, Bv[3] + 16, bufB + (size_t)16 * P256);
    conv4_k<32, 32, true, 8, bf16, bf16><<<c256, blk, 0, stream>>>(bufB, Wv[4], Bv[4], bufA);
    conv4_k<32, 32, true, 8, bf16, bf16><<<c256, blk, 0, stream>>>(bufB, Wv[4] + WOFF, Bv[4] + 16, bufA + (size_t)16 * P256);
    conv4_k<32, 32, true, 8, bf16, bf16><<<c256, blk, 0, stream>>>(bufA, Wv[5], Bv[5], bufB);
    conv4_k<32, 32, true, 8, bf16, bf16><<<c256, blk, 0, stream>>>(bufA, Wv[5] + WOFF, Bv[5] + 16, bufB + (size_t)16 * P256);

    // u = convT(e) + d   (in place over du)
    convT_add_k<<<dim3(P256 / BDIM, 4), blk, 0, stream>>>(bufB, wt, bt, du);

    // feats = conv8(relu(conv7(relu(conv6(u)))))
    conv4_k<32, 16, true,  9, bf16, bf16><<<c512, blk, 0, stream>>>(du,   Wv[6], Bv[6], bufA);
    conv4_k<16, 16, true,  9, bf16, bf16><<<c512, blk, 0, stream>>>(bufA, Wv[7], Bv[7], bufB);
    conv4_k<16, 16, false, 9, bf16, bf16><<<c512, blk, 0, stream>>>(bufB, Wv[8], Bv[8], bufA);

    // bilateral over concat(x[:, :11], feats), emit 11 channels
    bilateral2_k<<<b512, blk, 0, stream>>>(x, bufA, fp, out);

    (void)n_in; (void)out_size; (void)ws_size;
}

// Round 5
// 842.322 us; speedup vs baseline: 1.4980x; 1.2906x over previous
//
#include <hip/hip_runtime.h>
#include <hip/hip_bf16.h>
#include <cstdint>
#include <cstddef>

typedef __hip_bfloat16 bf16;
typedef __attribute__((ext_vector_type(8))) short bfrag8;   // 8 bf16 = 4 VGPR
typedef __attribute__((ext_vector_type(4))) float f32x4;    // MFMA acc

// ---- bf16 bit helpers ------------------------------------------------------
__device__ __forceinline__ float bfu2f(unsigned int u16) {
    unsigned int w = u16 << 16;
    float f; __builtin_memcpy(&f, &w, 4); return f;
}
__device__ __forceinline__ unsigned short f2bfu(float f) {
    bf16 h = __float2bfloat16(f);
    unsigned short u; __builtin_memcpy(&u, &h, 2); return u;
}
__device__ __forceinline__ void unpk8(const uint4 u, float* f) {
    f[0] = bfu2f(u.x & 0xffffu); f[1] = bfu2f(u.x >> 16);
    f[2] = bfu2f(u.y & 0xffffu); f[3] = bfu2f(u.y >> 16);
    f[4] = bfu2f(u.z & 0xffffu); f[5] = bfu2f(u.z >> 16);
    f[6] = bfu2f(u.w & 0xffffu); f[7] = bfu2f(u.w >> 16);
}

// ---------------------------------------------------------------------------
// Weight prep: OIHW f32 -> MFMA A-fragment bf16 layout.
// CIN==32: one tap per K=32 MFMA group (NT=9), kk = ci.
// CIN==16: two taps per K=32 group (NT=6): kk<16 -> kx=p*2+0, kk>=16 -> kx=p*2+1
//          (kx==3 is zero padding).
// A[m=co][k]: lane = (co%16) + 16*(kk>>3), elem j = kk&7.
// ---------------------------------------------------------------------------
struct WSrc { const float* w[9]; };

__global__ __launch_bounds__(256) void prep_k(WSrc src, bf16* __restrict__ wp) {
    const int l = blockIdx.x;
    const int CI[9]  = {16, 16, 16, 32, 32, 32, 32, 16, 16};
    const int CO[9]  = {16, 16, 32, 32, 32, 32, 16, 16, 16};
    const int OFF[9] = {0, 3072, 6144, 12288, 21504, 30720, 39936, 44544, 47616};
    const int cin = CI[l], cout = CO[l], nct = cout / 16;
    const int nt = (cin == 32) ? 9 : 6;
    const int sz = nt * nct * 512;
    const float* w = src.w[l];
    bf16* dst = wp + OFF[l];
    for (int e = threadIdx.x; e < sz; e += 256) {
        const int j = e & 7;
        const int lane = (e >> 3) & 63;
        const int r = e >> 9;
        const int ct = r % nct, tp = r / nct;
        const int co = ct * 16 + (lane & 15);
        const int kk = ((lane >> 4) << 3) + j;
        float v;
        if (cin == 32) {
            const int ci = kk, ky = tp / 3, kx = tp % 3;
            v = w[((co * 32 + ci) * 3 + ky) * 3 + kx];
        } else {
            const int ci = kk & 15, dxs = kk >> 4;
            const int ky = tp >> 1, kx = (tp & 1) * 2 + dxs;
            v = (kx < 3) ? w[((co * 16 + ci) * 3 + ky) * 3 + kx] : 0.0f;
        }
        dst[e] = __float2bfloat16(v);
    }
}

// ---------------------------------------------------------------------------
// x (NCHW f32, 16ch) -> NHWC bf16
// ---------------------------------------------------------------------------
__global__ __launch_bounds__(256) void xtonhwc_k(
    const float* __restrict__ x, bf16* __restrict__ xh)
{
    const int idx = blockIdx.x * 256 + threadIdx.x;   // 4*262144
    const int n = idx >> 18, px = idx & 262143;
    const float* xp = x + (size_t)n * 16 * 262144 + px;
    unsigned short r[16];
    #pragma unroll
    for (int c = 0; c < 16; ++c) r[c] = f2bfu(xp[(size_t)c * 262144]);
    __builtin_memcpy(xh + (size_t)idx * 16, r, 32);
}

// ---------------------------------------------------------------------------
// Implicit-GEMM 3x3 SAME conv with MFMA 16x16x32 bf16, NHWC.
// Wave: 64 px (4 N-tiles of 16) x COUT. Block: 4 waves = 256 px (row-aligned).
// C/D: px = lane&15 (col), co = (lane>>4)*4 + reg (row)  [m89-verified].
// A/B: k = (lane>>4)*8 + j; A row / B col = lane&15.
// ---------------------------------------------------------------------------
template<int CIN, int COUT, bool RELU, int LW>
__global__ __launch_bounds__(256) void convm_k(
    const bf16* __restrict__ in, const bf16* __restrict__ wp,
    const float* __restrict__ bias, bf16* __restrict__ out)
{
    constexpr int Wd = 1 << LW;
    constexpr int PLANE = Wd * Wd;
    constexpr int NCT = COUT / 16;
    constexpr int NT = (CIN == 32) ? 9 : 6;
    constexpr int CB = CIN * 2;                 // bytes per pixel

    const int lane = threadIdx.x & 63;
    const int l4 = lane >> 4;
    const int lm = lane & 15;
    const int wv = threadIdx.x >> 6;
    const int n = blockIdx.y;
    const int pxb = blockIdx.x * 256 + wv * 64; // wave's first px (row-aligned)
    const int y = pxb >> LW;                    // uniform within block
    const int xw = pxb & (Wd - 1);

    // A fragments (prepped weights)
    bfrag8 afr[NT][NCT];
    #pragma unroll
    for (int tp = 0; tp < NT; ++tp)
        #pragma unroll
        for (int ct = 0; ct < NCT; ++ct)
            __builtin_memcpy(&afr[tp][ct],
                wp + ((size_t)(tp * NCT + ct) * 64 + lane) * 8, 16);

    // acc init = bias
    f32x4 acc[4][NCT];
    #pragma unroll
    for (int ct = 0; ct < NCT; ++ct) {
        const float4 bv = *reinterpret_cast<const float4*>(bias + ct * 16 + l4 * 4);
        #pragma unroll
        for (int t = 0; t < 4; ++t) {
            acc[t][ct][0] = bv.x; acc[t][ct][1] = bv.y;
            acc[t][ct][2] = bv.z; acc[t][ct][3] = bv.w;
        }
    }

    // per-lane x-edge masks (CIN==16: lanes>=32 hold the +1-shifted tap, never
    // the edge tap, so they are always ok)
    bool okL[4], okR[4];
    #pragma unroll
    for (int t = 0; t < 4; ++t) {
        const int xl = xw + t * 16 + lm;
        okL[t] = (xl != 0)      || (CIN == 16 && lane >= 32);
        okR[t] = (xl != Wd - 1) || (CIN == 16 && lane >= 32);
    }

    // per-lane base byte offset inside a row tile
    int laneoff;
    if (CIN == 32) laneoff = lm * 64 + l4 * 16;
    else           laneoff = lm * 32 + (l4 >> 1) * 32 + (l4 & 1) * 16;

    const char* base = (const char*)in
        + ((size_t)n * PLANE + (size_t)y * Wd + xw) * CB + laneoff;

    #pragma unroll
    for (int ky = 0; ky < 3; ++ky) {
        if ((unsigned)(y + ky - 1) >= (unsigned)Wd) continue;   // uniform skip
        const char* rb = base + (ky - 1) * Wd * CB;
        if (CIN == 32) {
            #pragma unroll
            for (int dx = 0; dx < 3; ++dx) {
                #pragma unroll
                for (int t = 0; t < 4; ++t) {
                    uint4 u = *reinterpret_cast<const uint4*>(rb + ((dx - 1) + t * 16) * 64);
                    if (dx == 0 && !okL[t]) { u.x = 0; u.y = 0; u.z = 0; u.w = 0; }
                    if (dx == 2 && !okR[t]) { u.x = 0; u.y = 0; u.z = 0; u.w = 0; }
                    bfrag8 b; __builtin_memcpy(&b, &u, 16);
                    #pragma unroll
                    for (int ct = 0; ct < NCT; ++ct)
                        acc[t][ct] = __builtin_amdgcn_mfma_f32_16x16x32_bf16(
                            afr[ky * 3 + dx][ct], b, acc[t][ct], 0, 0, 0);
                }
            }
        } else {
            #pragma unroll
            for (int p = 0; p < 2; ++p) {
                #pragma unroll
                for (int t = 0; t < 4; ++t) {
                    uint4 u = *reinterpret_cast<const uint4*>(rb + (p ? 32 : -32) + t * 512);
                    if (p == 0 && !okL[t]) { u.x = 0; u.y = 0; u.z = 0; u.w = 0; }
                    if (p == 1 && !okR[t]) { u.x = 0; u.y = 0; u.z = 0; u.w = 0; }
                    bfrag8 b; __builtin_memcpy(&b, &u, 16);
                    #pragma unroll
                    for (int ct = 0; ct < NCT; ++ct)
                        acc[t][ct] = __builtin_amdgcn_mfma_f32_16x16x32_bf16(
                            afr[ky * 2 + p][ct], b, acc[t][ct], 0, 0, 0);
                }
            }
        }
    }

    char* ob = (char*)out + ((size_t)n * PLANE + (size_t)y * Wd + xw) * (COUT * 2);
    #pragma unroll
    for (int t = 0; t < 4; ++t)
        #pragma unroll
        for (int ct = 0; ct < NCT; ++ct) {
            float a0 = acc[t][ct][0], a1 = acc[t][ct][1];
            float a2 = acc[t][ct][2], a3 = acc[t][ct][3];
            if (RELU) {
                a0 = fmaxf(a0, 0.f); a1 = fmaxf(a1, 0.f);
                a2 = fmaxf(a2, 0.f); a3 = fmaxf(a3, 0.f);
            }
            ushort4 pk;
            pk.x = f2bfu(a0); pk.y = f2bfu(a1); pk.z = f2bfu(a2); pk.w = f2bfu(a3);
            *reinterpret_cast<ushort4*>(
                ob + ((size_t)(t * 16 + lm) * COUT + ct * 16 + l4 * 4) * 2) = pk;
        }
}

// ---------------------------------------------------------------------------
// 2x2 maxpool NHWC 32ch: (4,512,512,32) -> (4,256,256,32). Thread = (opx, 8ch).
// ---------------------------------------------------------------------------
__global__ __launch_bounds__(256) void pool_k(
    const bf16* __restrict__ in, bf16* __restrict__ out)
{
    const int idx = blockIdx.x * 256 + threadIdx.x;   // 4*65536*4
    const int c8 = (idx & 3) * 8;
    const int opx = idx >> 2;
    const int n = opx >> 16;
    const int p = opx & 65535;
    const int oy = p >> 8, ox = p & 255;
    const char* ip = (const char*)in
        + (((size_t)n * 262144 + (size_t)(2 * oy) * 512 + 2 * ox) * 32 + c8) * 2;
    uint4 ua = *reinterpret_cast<const uint4*>(ip);
    uint4 ub = *reinterpret_cast<const uint4*>(ip + 64);
    uint4 uc = *reinterpret_cast<const uint4*>(ip + 512 * 64);
    uint4 ud = *reinterpret_cast<const uint4*>(ip + 512 * 64 + 64);
    float a[8], b[8], c[8], d[8];
    unpk8(ua, a); unpk8(ub, b); unpk8(uc, c); unpk8(ud, d);
    unsigned short r[8];
    #pragma unroll
    for (int k = 0; k < 8; ++k)
        r[k] = f2bfu(fmaxf(fmaxf(a[k], b[k]), fmaxf(c[k], d[k])));
    __builtin_memcpy((char*)out + (((size_t)n * 65536 + p) * 32 + c8) * 2, r, 16);
}

// ---------------------------------------------------------------------------
// ConvT 2x2 s2 + skip add, NHWC, in-place over du.
// ---------------------------------------------------------------------------
__global__ __launch_bounds__(256) void convT_k(
    const bf16* __restrict__ e, const float* __restrict__ wt,
    const float* __restrict__ bt, bf16* __restrict__ du)
{
    const int pix = blockIdx.x * 256 + threadIdx.x;   // 65536/img
    const int n = blockIdx.y;
    const int i = pix >> 8, j = pix & 255;

    const char* ep = (const char*)e + ((size_t)n * 65536 + pix) * 64;
    float ev[32];
    {
        uint4 u0 = *reinterpret_cast<const uint4*>(ep);
        uint4 u1 = *reinterpret_cast<const uint4*>(ep + 16);
        uint4 u2 = *reinterpret_cast<const uint4*>(ep + 32);
        uint4 u3 = *reinterpret_cast<const uint4*>(ep + 48);
        unpk8(u0, ev); unpk8(u1, ev + 8); unpk8(u2, ev + 16); unpk8(u3, ev + 24);
    }

    #pragma unroll
    for (int ab = 0; ab < 4; ++ab) {
        const int a = ab >> 1, b = ab & 1;
        float acc[32];
        #pragma unroll
        for (int co = 0; co < 32; ++co) acc[co] = bt[co];
        #pragma unroll
        for (int ci = 0; ci < 32; ++ci) {
            const float v = ev[ci];
            #pragma unroll
            for (int co = 0; co < 32; ++co)
                acc[co] = fmaf(v, wt[(ci * 32 + co) * 4 + ab], acc[co]);
        }
        char* dp = (char*)du
            + ((size_t)n * 262144 + (size_t)(2 * i + a) * 512 + (2 * j + b)) * 64;
        #pragma unroll
        for (int q = 0; q < 4; ++q) {
            uint4 u = *reinterpret_cast<const uint4*>(dp + q * 16);
            float dv[8]; unpk8(u, dv);
            unsigned short r[8];
            #pragma unroll
            for (int k = 0; k < 8; ++k) r[k] = f2bfu(dv[k] + acc[q * 8 + k]);
            __builtin_memcpy(dp + q * 16, r, 16);
        }
    }
}

// ---------------------------------------------------------------------------
// Bilateral: x NCHW f32 (11 ch used), feats NHWC bf16 16ch. 1 px/thread.
// ---------------------------------------------------------------------------
__global__ __launch_bounds__(256) void bil_k(
    const float* __restrict__ xin, const bf16* __restrict__ feats,
    const float* __restrict__ fp, float* __restrict__ out)
{
    constexpr int PLANE = 512 * 512;
    const int pix = blockIdx.x * 256 + threadIdx.x;
    const int n = blockIdx.y;
    const int y = pix >> 9, xx = pix & 511;

    float cw[27];
    #pragma unroll
    for (int i = 0; i < 27; ++i) cw[i] = fp[i];
    const float sy = fp[27], sx = fp[28];

    const float* xb = xin + (size_t)n * 16 * PLANE + pix;
    const char* fb = (const char*)feats + ((size_t)n * PLANE + pix) * 32;

    float c[27];
    #pragma unroll
    for (int i = 0; i < 11; ++i) c[i] = xb[(size_t)i * PLANE];
    {
        uint4 u0 = *reinterpret_cast<const uint4*>(fb);
        uint4 u1 = *reinterpret_cast<const uint4*>(fb + 16);
        unpk8(u0, c + 11); unpk8(u1, c + 19);
    }

    float num[11];
    #pragma unroll
    for (int i = 0; i < 11; ++i) num[i] = 0.0f;
    float den = 0.0f;

    #pragma unroll
    for (int dy = -2; dy <= 2; ++dy) {
        const int yy = y + 2 * dy;
        if ((unsigned)yy > 511u) continue;            // uniform per block
        #pragma unroll
        for (int dx = -2; dx <= 2; ++dx) {
            const int xv = xx + 2 * dx;
            if ((unsigned)xv > 511u) continue;        // edge lanes only
            const int off = dy * 1024 + dx * 2;       // px offset
            float lw = sy * (float)(4 * dy * dy) + sx * (float)(4 * dx * dx);
            float shv[11];
            #pragma unroll
            for (int i = 0; i < 11; ++i) {
                const float s = xb[(size_t)i * PLANE + off];
                shv[i] = s;
                const float d = s - c[i];
                lw = fmaf(cw[i], d * d, lw);
            }
            const char* fq = fb + (ptrdiff_t)off * 32;
            uint4 u0 = *reinterpret_cast<const uint4*>(fq);
            uint4 u1 = *reinterpret_cast<const uint4*>(fq + 16);
            float fv[16];
            unpk8(u0, fv); unpk8(u1, fv + 8);
            #pragma unroll
            for (int i = 0; i < 16; ++i) {
                const float d = fv[i] - c[11 + i];
                lw = fmaf(cw[11 + i], d * d, lw);
            }
            const float w = __expf(lw);
            #pragma unroll
            for (int i = 0; i < 11; ++i) num[i] = fmaf(w, shv[i], num[i]);
            den += w;
        }
    }

    const float inv = 1.0f / den;
    float* ob = out + (size_t)n * 11 * PLANE + pix;
    #pragma unroll
    for (int i = 0; i < 11; ++i) ob[(size_t)i * PLANE] = num[i] * inv;
}

// ---------------------------------------------------------------------------
extern "C" void kernel_launch(void* const* d_in, const int* in_sizes, int n_in,
                              void* d_out, int out_size, void* d_ws, size_t ws_size,
                              hipStream_t stream)
{
    const float* x = (const float*)d_in[0];
    const float* Wv[9];
    const float* Bv[9];
    if (in_sizes[2] == 16) {
        for (int i = 0; i < 9; ++i) {            // dict order x,w0,b0,w1,b1,...
            Wv[i] = (const float*)d_in[1 + 2 * i];
            Bv[i] = (const float*)d_in[2 + 2 * i];
        }
    } else {
        for (int i = 0; i < 9; ++i) {            // signature order fallback
            Wv[i] = (const float*)d_in[1 + i];
            Bv[i] = (const float*)d_in[10 + i];
        }
    }
    const float* wt = (const float*)d_in[19];
    const float* bt = (const float*)d_in[20];
    const float* fp = (const float*)d_in[21];
    float* out = (float*)d_out;

    constexpr size_t MiB = 1ull << 20;
    char* ws = (char*)d_ws;

    // wp: 50688 bf16 (~100KB) at ws+4K. NHWC activation buffers (each with
    // >=1MiB guard spacing; conv reads may stray +-64B past image bounds):
    bf16* wp = (bf16*)(ws + 4096);
    bf16 *xh, *du, *bufA, *bufB;
    if (ws_size >= 165 * MiB) {
        xh   = (bf16*)(ws + 1 * MiB);    // 32M
        du   = (bf16*)(ws + 34 * MiB);   // 64M
        bufA = (bf16*)(ws + 99 * MiB);   // 32M
        bufB = (bf16*)(ws + 132 * MiB);  // 32M
    } else if (ws_size >= 132 * MiB) {
        xh   = (bf16*)(ws + 1 * MiB);    // xh dead after conv0; reused as bufB
        du   = (bf16*)(ws + 34 * MiB);
        bufA = (bf16*)(ws + 99 * MiB);
        bufB = xh;
    } else {
        // tight: xh and bufB live in d_out (46.1MB; dead before final write)
        xh   = (bf16*)((char*)d_out + 256);
        du   = (bf16*)(ws + 1 * MiB);
        bufA = (bf16*)(ws + 66 * MiB);
        bufB = xh;
    }

    WSrc srcs;
    for (int i = 0; i < 9; ++i) srcs.w[i] = Wv[i];

    prep_k<<<9, 256, 0, stream>>>(srcs, wp);
    xtonhwc_k<<<4096, 256, 0, stream>>>(x, xh);

    const dim3 blk(256);
    const dim3 g512(1024, 4), g256(256, 4);

    convm_k<16, 16, true,  9><<<g512, blk, 0, stream>>>(xh,   wp + 0,     Bv[0], bufA);
    convm_k<16, 16, true,  9><<<g512, blk, 0, stream>>>(bufA, wp + 3072,  Bv[1], bufB);
    convm_k<16, 32, false, 9><<<g512, blk, 0, stream>>>(bufB, wp + 6144,  Bv[2], du);

    pool_k<<<4096, blk, 0, stream>>>(du, bufA);
    convm_k<32, 32, true, 8><<<g256, blk, 0, stream>>>(bufA, wp + 12288, Bv[3], bufB);
    convm_k<32, 32, true, 8><<<g256, blk, 0, stream>>>(bufB, wp + 21504, Bv[4], bufA);
    convm_k<32, 32, true, 8><<<g256, blk, 0, stream>>>(bufA, wp + 30720, Bv[5], bufB);

    convT_k<<<g256, blk, 0, stream>>>(bufB, wt, bt, du);

    convm_k<32, 16, true,  9><<<g512, blk, 0, stream>>>(du,   wp + 39936, Bv[6], bufA);
    convm_k<16, 16, true,  9><<<g512, blk, 0, stream>>>(bufA, wp + 44544, Bv[7], bufB);
    convm_k<16, 16, false, 9><<<g512, blk, 0, stream>>>(bufB, wp + 47616, Bv[8], bufA);

    bil_k<<<g512, blk, 0, stream>>>(x, bufA, fp, out);

    (void)n_in; (void)out_size;
}

// Round 6
// 433.546 us; speedup vs baseline: 2.9105x; 1.9429x over previous
//
#include <hip/hip_runtime.h>
#include <hip/hip_bf16.h>
#include <cstdint>
#include <cstddef>

typedef __hip_bfloat16 bf16;
typedef __attribute__((ext_vector_type(8))) short bfrag8;   // 8 bf16 = 4 VGPR
typedef __attribute__((ext_vector_type(4))) float f32x4;    // MFMA acc

// ---- bf16 bit helpers ------------------------------------------------------
__device__ __forceinline__ float bfu2f(unsigned int u16) {
    unsigned int w = u16 << 16;
    float f; __builtin_memcpy(&f, &w, 4); return f;
}
__device__ __forceinline__ unsigned short f2bfu(float f) {
    bf16 h = __float2bfloat16(f);
    unsigned short u; __builtin_memcpy(&u, &h, 2); return u;
}
__device__ __forceinline__ void unpk8(const uint4 u, float* f) {
    f[0] = bfu2f(u.x & 0xffffu); f[1] = bfu2f(u.x >> 16);
    f[2] = bfu2f(u.y & 0xffffu); f[3] = bfu2f(u.y >> 16);
    f[4] = bfu2f(u.z & 0xffffu); f[5] = bfu2f(u.z >> 16);
    f[6] = bfu2f(u.w & 0xffffu); f[7] = bfu2f(u.w >> 16);
}

// ---------------------------------------------------------------------------
// Weight prep: OIHW f32 -> MFMA A-fragment bf16 layout (3x3 convs).
// ---------------------------------------------------------------------------
struct WSrc { const float* w[9]; };

__global__ __launch_bounds__(256) void prep_k(WSrc src, bf16* __restrict__ wp) {
    const int l = blockIdx.x;
    const int CI[9]  = {16, 16, 16, 32, 32, 32, 32, 16, 16};
    const int CO[9]  = {16, 16, 32, 32, 32, 32, 16, 16, 16};
    const int OFF[9] = {0, 3072, 6144, 12288, 21504, 30720, 39936, 44544, 47616};
    const int cin = CI[l], cout = CO[l], nct = cout / 16;
    const int nt = (cin == 32) ? 9 : 6;
    const int sz = nt * nct * 512;
    const float* w = src.w[l];
    bf16* dst = wp + OFF[l];
    for (int e = threadIdx.x; e < sz; e += 256) {
        const int j = e & 7;
        const int lane = (e >> 3) & 63;
        const int r = e >> 9;
        const int ct = r % nct, tp = r / nct;
        const int co = ct * 16 + (lane & 15);
        const int kk = ((lane >> 4) << 3) + j;
        float v;
        if (cin == 32) {
            const int ci = kk, ky = tp / 3, kx = tp % 3;
            v = w[((co * 32 + ci) * 3 + ky) * 3 + kx];
        } else {
            const int ci = kk & 15, dxs = kk >> 4;
            const int ky = tp >> 1, kx = (tp & 1) * 2 + dxs;
            v = (kx < 3) ? w[((co * 16 + ci) * 3 + ky) * 3 + kx] : 0.0f;
        }
        dst[e] = __float2bfloat16(v);
    }
}

// ---------------------------------------------------------------------------
// ConvT weight prep: wt[ci][co][a][b] f32 -> A-fragment bf16, m = co*4+ab,
// k = ci.  A lane l holds row m=l&15, k=(l>>4)*8+j  (same layout convm uses).
// ---------------------------------------------------------------------------
__global__ __launch_bounds__(256) void prep2_k(
    const float* __restrict__ wt, bf16* __restrict__ wpT)
{
    for (int e = threadIdx.x; e < 4096; e += 256) {
        const int j = e & 7;
        const int lane = (e >> 3) & 63;
        const int mt = e >> 9;
        const int m = mt * 16 + (lane & 15);
        const int k = ((lane >> 4) << 3) + j;     // ci
        wpT[e] = __float2bfloat16(wt[k * 128 + m]);   // m = co*4 + a*2 + b
    }
}

// ---------------------------------------------------------------------------
// x (NCHW f32, 16ch) -> NHWC bf16
// ---------------------------------------------------------------------------
__global__ __launch_bounds__(256) void xtonhwc_k(
    const float* __restrict__ x, bf16* __restrict__ xh)
{
    const int idx = blockIdx.x * 256 + threadIdx.x;   // 4*262144
    const int n = idx >> 18, px = idx & 262143;
    const float* xp = x + (size_t)n * 16 * 262144 + px;
    unsigned short r[16];
    #pragma unroll
    for (int c = 0; c < 16; ++c) r[c] = f2bfu(xp[(size_t)c * 262144]);
    __builtin_memcpy(xh + (size_t)idx * 16, r, 32);
}

// ---------------------------------------------------------------------------
// Implicit-GEMM 3x3 SAME conv with MFMA 16x16x32 bf16, NHWC (unchanged, R5).
// ---------------------------------------------------------------------------
template<int CIN, int COUT, bool RELU, int LW>
__global__ __launch_bounds__(256) void convm_k(
    const bf16* __restrict__ in, const bf16* __restrict__ wp,
    const float* __restrict__ bias, bf16* __restrict__ out)
{
    constexpr int Wd = 1 << LW;
    constexpr int PLANE = Wd * Wd;
    constexpr int NCT = COUT / 16;
    constexpr int NT = (CIN == 32) ? 9 : 6;
    constexpr int CB = CIN * 2;

    const int lane = threadIdx.x & 63;
    const int l4 = lane >> 4;
    const int lm = lane & 15;
    const int wv = threadIdx.x >> 6;
    const int n = blockIdx.y;
    const int pxb = blockIdx.x * 256 + wv * 64;
    const int y = pxb >> LW;
    const int xw = pxb & (Wd - 1);

    bfrag8 afr[NT][NCT];
    #pragma unroll
    for (int tp = 0; tp < NT; ++tp)
        #pragma unroll
        for (int ct = 0; ct < NCT; ++ct)
            __builtin_memcpy(&afr[tp][ct],
                wp + ((size_t)(tp * NCT + ct) * 64 + lane) * 8, 16);

    f32x4 acc[4][NCT];
    #pragma unroll
    for (int ct = 0; ct < NCT; ++ct) {
        const float4 bv = *reinterpret_cast<const float4*>(bias + ct * 16 + l4 * 4);
        #pragma unroll
        for (int t = 0; t < 4; ++t) {
            acc[t][ct][0] = bv.x; acc[t][ct][1] = bv.y;
            acc[t][ct][2] = bv.z; acc[t][ct][3] = bv.w;
        }
    }

    bool okL[4], okR[4];
    #pragma unroll
    for (int t = 0; t < 4; ++t) {
        const int xl = xw + t * 16 + lm;
        okL[t] = (xl != 0)      || (CIN == 16 && lane >= 32);
        okR[t] = (xl != Wd - 1) || (CIN == 16 && lane >= 32);
    }

    int laneoff;
    if (CIN == 32) laneoff = lm * 64 + l4 * 16;
    else           laneoff = lm * 32 + (l4 >> 1) * 32 + (l4 & 1) * 16;

    const char* base = (const char*)in
        + ((size_t)n * PLANE + (size_t)y * Wd + xw) * CB + laneoff;

    #pragma unroll
    for (int ky = 0; ky < 3; ++ky) {
        if ((unsigned)(y + ky - 1) >= (unsigned)Wd) continue;
        const char* rb = base + (ky - 1) * Wd * CB;
        if (CIN == 32) {
            #pragma unroll
            for (int dx = 0; dx < 3; ++dx) {
                #pragma unroll
                for (int t = 0; t < 4; ++t) {
                    uint4 u = *reinterpret_cast<const uint4*>(rb + ((dx - 1) + t * 16) * 64);
                    if (dx == 0 && !okL[t]) { u.x = 0; u.y = 0; u.z = 0; u.w = 0; }
                    if (dx == 2 && !okR[t]) { u.x = 0; u.y = 0; u.z = 0; u.w = 0; }
                    bfrag8 b; __builtin_memcpy(&b, &u, 16);
                    #pragma unroll
                    for (int ct = 0; ct < NCT; ++ct)
                        acc[t][ct] = __builtin_amdgcn_mfma_f32_16x16x32_bf16(
                            afr[ky * 3 + dx][ct], b, acc[t][ct], 0, 0, 0);
                }
            }
        } else {
            #pragma unroll
            for (int p = 0; p < 2; ++p) {
                #pragma unroll
                for (int t = 0; t < 4; ++t) {
                    uint4 u = *reinterpret_cast<const uint4*>(rb + (p ? 32 : -32) + t * 512);
                    if (p == 0 && !okL[t]) { u.x = 0; u.y = 0; u.z = 0; u.w = 0; }
                    if (p == 1 && !okR[t]) { u.x = 0; u.y = 0; u.z = 0; u.w = 0; }
                    bfrag8 b; __builtin_memcpy(&b, &u, 16);
                    #pragma unroll
                    for (int ct = 0; ct < NCT; ++ct)
                        acc[t][ct] = __builtin_amdgcn_mfma_f32_16x16x32_bf16(
                            afr[ky * 2 + p][ct], b, acc[t][ct], 0, 0, 0);
                }
            }
        }
    }

    char* ob = (char*)out + ((size_t)n * PLANE + (size_t)y * Wd + xw) * (COUT * 2);
    #pragma unroll
    for (int t = 0; t < 4; ++t)
        #pragma unroll
        for (int ct = 0; ct < NCT; ++ct) {
            float a0 = acc[t][ct][0], a1 = acc[t][ct][1];
            float a2 = acc[t][ct][2], a3 = acc[t][ct][3];
            if (RELU) {
                a0 = fmaxf(a0, 0.f); a1 = fmaxf(a1, 0.f);
                a2 = fmaxf(a2, 0.f); a3 = fmaxf(a3, 0.f);
            }
            ushort4 pk;
            pk.x = f2bfu(a0); pk.y = f2bfu(a1); pk.z = f2bfu(a2); pk.w = f2bfu(a3);
            *reinterpret_cast<ushort4*>(
                ob + ((size_t)(t * 16 + lm) * COUT + ct * 16 + l4 * 4) * 2) = pk;
        }
}

// ---------------------------------------------------------------------------
// 2x2 maxpool NHWC 32ch (unchanged).
// ---------------------------------------------------------------------------
__global__ __launch_bounds__(256) void pool_k(
    const bf16* __restrict__ in, bf16* __restrict__ out)
{
    const int idx = blockIdx.x * 256 + threadIdx.x;
    const int c8 = (idx & 3) * 8;
    const int opx = idx >> 2;
    const int n = opx >> 16;
    const int p = opx & 65535;
    const int oy = p >> 8, ox = p & 255;
    const char* ip = (const char*)in
        + (((size_t)n * 262144 + (size_t)(2 * oy) * 512 + 2 * ox) * 32 + c8) * 2;
    uint4 ua = *reinterpret_cast<const uint4*>(ip);
    uint4 ub = *reinterpret_cast<const uint4*>(ip + 64);
    uint4 uc = *reinterpret_cast<const uint4*>(ip + 512 * 64);
    uint4 ud = *reinterpret_cast<const uint4*>(ip + 512 * 64 + 64);
    float a[8], b[8], c[8], d[8];
    unpk8(ua, a); unpk8(ub, b); unpk8(uc, c); unpk8(ud, d);
    unsigned short r[8];
    #pragma unroll
    for (int k = 0; k < 8; ++k)
        r[k] = f2bfu(fmaxf(fmaxf(a[k], b[k]), fmaxf(c[k], d[k])));
    __builtin_memcpy((char*)out + (((size_t)n * 65536 + p) * 32 + c8) * 2, r, 16);
}

// ---------------------------------------------------------------------------
// ConvT 2x2 s2 + skip add via MFMA.  GEMM: C[m=co*4+ab][n=px] = wt^T @ e.
// Wave = 64 px (one quarter of a low-res row), 8 m-tiles, 4 n-tiles.
// Epilogue: acc -> LDS (pad-132 rows, b128-aligned) -> coalesced 64B RMW
// of du: lanes 0..31 handle output row 2i (a=0), lanes 32..63 row 2i+1.
// ---------------------------------------------------------------------------
__global__ __launch_bounds__(256) void convTm_k(
    const bf16* __restrict__ e, const bf16* __restrict__ wpT,
    const float* __restrict__ bt, bf16* __restrict__ du)
{
    __shared__ float lds[4][16 * 132];        // per-wave 16px x 128m (stride 132)
    const int lane = threadIdx.x & 63;
    const int wv = threadIdx.x >> 6;
    const int l4 = lane >> 4, lm = lane & 15;
    const int n = blockIdx.y;
    const int row = blockIdx.x;               // low-res row i, 0..255
    const int j0 = wv * 64;                   // wave's first j

    bfrag8 afr[8];
    #pragma unroll
    for (int mt = 0; mt < 8; ++mt)
        __builtin_memcpy(&afr[mt], wpT + ((size_t)(mt * 64 + lane)) * 8, 16);

    float bco[8];                             // bias for co = mt*4 + l4
    #pragma unroll
    for (int mt = 0; mt < 8; ++mt) bco[mt] = bt[mt * 4 + l4];

    const char* ep = (const char*)e + ((size_t)n * 65536 + (size_t)row * 256 + j0) * 64;
    float* L = lds[wv];

    // reader-lane constants
    const int ra = lane >> 5;                 // output row parity a
    const int ru = lane & 31;
    const int rj = ru >> 1;                   // local px 0..15
    const int rb = ru & 1;                    // output col parity b

    #pragma unroll 1
    for (int nt = 0; nt < 4; ++nt) {
        bfrag8 bf;
        __builtin_memcpy(&bf, ep + (nt * 16 + lm) * 64 + l4 * 16, 16);

        #pragma unroll
        for (int mt = 0; mt < 8; ++mt) {
            f32x4 acc;
            acc[0] = bco[mt]; acc[1] = bco[mt]; acc[2] = bco[mt]; acc[3] = bco[mt];
            acc = __builtin_amdgcn_mfma_f32_16x16x32_bf16(afr[mt], bf, acc, 0, 0, 0);
            float4 st; st.x = acc[0]; st.y = acc[1]; st.z = acc[2]; st.w = acc[3];
            *reinterpret_cast<float4*>(L + lm * 132 + mt * 16 + l4 * 4) = st;
        }
        __syncthreads();

        // RMW du: (y,x) = (2*row + ra, 2*(j0 + nt*16 + rj) + rb), 32 ch x bf16
        {
            const float* Ls = L + rj * 132 + ra * 2 + rb;   // + co*4 strides
            char* dp = (char*)du
                + (((size_t)n * 262144
                    + (size_t)(2 * row + ra) * 512
                    + (size_t)(2 * (j0 + nt * 16 + rj) + rb)) * 32) * 2;
            float add[32];
            #pragma unroll
            for (int co = 0; co < 32; ++co) add[co] = Ls[co * 4];
            #pragma unroll
            for (int q = 0; q < 4; ++q) {
                uint4 u = *reinterpret_cast<const uint4*>(dp + q * 16);
                float dv[8]; unpk8(u, dv);
                unsigned short r[8];
                #pragma unroll
                for (int k = 0; k < 8; ++k) r[k] = f2bfu(dv[k] + add[q * 8 + k]);
                __builtin_memcpy(dp + q * 16, r, 16);
            }
        }
        __syncthreads();
    }
}

// ---------------------------------------------------------------------------
// Bilateral (unchanged, R5): x NCHW f32 (11 ch), feats NHWC bf16.
// ---------------------------------------------------------------------------
__global__ __launch_bounds__(256) void bil_k(
    const float* __restrict__ xin, const bf16* __restrict__ feats,
    const float* __restrict__ fp, float* __restrict__ out)
{
    constexpr int PLANE = 512 * 512;
    const int pix = blockIdx.x * 256 + threadIdx.x;
    const int n = blockIdx.y;
    const int y = pix >> 9, xx = pix & 511;

    float cw[27];
    #pragma unroll
    for (int i = 0; i < 27; ++i) cw[i] = fp[i];
    const float sy = fp[27], sx = fp[28];

    const float* xb = xin + (size_t)n * 16 * PLANE + pix;
    const char* fb = (const char*)feats + ((size_t)n * PLANE + pix) * 32;

    float c[27];
    #pragma unroll
    for (int i = 0; i < 11; ++i) c[i] = xb[(size_t)i * PLANE];
    {
        uint4 u0 = *reinterpret_cast<const uint4*>(fb);
        uint4 u1 = *reinterpret_cast<const uint4*>(fb + 16);
        unpk8(u0, c + 11); unpk8(u1, c + 19);
    }

    float num[11];
    #pragma unroll
    for (int i = 0; i < 11; ++i) num[i] = 0.0f;
    float den = 0.0f;

    #pragma unroll
    for (int dy = -2; dy <= 2; ++dy) {
        const int yy = y + 2 * dy;
        if ((unsigned)yy > 511u) continue;
        #pragma unroll
        for (int dx = -2; dx <= 2; ++dx) {
            const int xv = xx + 2 * dx;
            if ((unsigned)xv > 511u) continue;
            const int off = dy * 1024 + dx * 2;
            float lw = sy * (float)(4 * dy * dy) + sx * (float)(4 * dx * dx);
            float shv[11];
            #pragma unroll
            for (int i = 0; i < 11; ++i) {
                const float s = xb[(size_t)i * PLANE + off];
                shv[i] = s;
                const float d = s - c[i];
                lw = fmaf(cw[i], d * d, lw);
            }
            const char* fq = fb + (ptrdiff_t)off * 32;
            uint4 u0 = *reinterpret_cast<const uint4*>(fq);
            uint4 u1 = *reinterpret_cast<const uint4*>(fq + 16);
            float fv[16];
            unpk8(u0, fv); unpk8(u1, fv + 8);
            #pragma unroll
            for (int i = 0; i < 16; ++i) {
                const float d = fv[i] - c[11 + i];
                lw = fmaf(cw[11 + i], d * d, lw);
            }
            const float w = __expf(lw);
            #pragma unroll
            for (int i = 0; i < 11; ++i) num[i] = fmaf(w, shv[i], num[i]);
            den += w;
        }
    }

    const float inv = 1.0f / den;
    float* ob = out + (size_t)n * 11 * PLANE + pix;
    #pragma unroll
    for (int i = 0; i < 11; ++i) ob[(size_t)i * PLANE] = num[i] * inv;
}

// ---------------------------------------------------------------------------
extern "C" void kernel_launch(void* const* d_in, const int* in_sizes, int n_in,
                              void* d_out, int out_size, void* d_ws, size_t ws_size,
                              hipStream_t stream)
{
    const float* x = (const float*)d_in[0];
    const float* Wv[9];
    const float* Bv[9];
    if (in_sizes[2] == 16) {
        for (int i = 0; i < 9; ++i) {
            Wv[i] = (const float*)d_in[1 + 2 * i];
            Bv[i] = (const float*)d_in[2 + 2 * i];
        }
    } else {
        for (int i = 0; i < 9; ++i) {
            Wv[i] = (const float*)d_in[1 + i];
            Bv[i] = (const float*)d_in[10 + i];
        }
    }
    const float* wt = (const float*)d_in[19];
    const float* bt = (const float*)d_in[20];
    const float* fp = (const float*)d_in[21];
    float* out = (float*)d_out;

    constexpr size_t MiB = 1ull << 20;
    char* ws = (char*)d_ws;

    bf16* wp  = (bf16*)(ws + 4096);           // ~100 KB of conv A-fragments
    bf16* wpT = (bf16*)(ws + 256 * 1024);     // 8 KB convT A-fragments
    bf16 *xh, *du, *bufA, *bufB;
    if (ws_size >= 165 * MiB) {
        xh   = (bf16*)(ws + 1 * MiB);
        du   = (bf16*)(ws + 34 * MiB);
        bufA = (bf16*)(ws + 99 * MiB);
        bufB = (bf16*)(ws + 132 * MiB);
    } else if (ws_size >= 132 * MiB) {
        xh   = (bf16*)(ws + 1 * MiB);
        du   = (bf16*)(ws + 34 * MiB);
        bufA = (bf16*)(ws + 99 * MiB);
        bufB = xh;                            // xh dead after conv0
    } else {
        xh   = (bf16*)((char*)d_out + 256);   // d_out as scratch (dead at end)
        du   = (bf16*)(ws + 1 * MiB);
        bufA = (bf16*)(ws + 66 * MiB);
        bufB = xh;
    }

    WSrc srcs;
    for (int i = 0; i < 9; ++i) srcs.w[i] = Wv[i];

    prep_k<<<9, 256, 0, stream>>>(srcs, wp);
    prep2_k<<<1, 256, 0, stream>>>(wt, wpT);
    xtonhwc_k<<<4096, 256, 0, stream>>>(x, xh);

    const dim3 blk(256);
    const dim3 g512(1024, 4), g256(256, 4);

    convm_k<16, 16, true,  9><<<g512, blk, 0, stream>>>(xh,   wp + 0,     Bv[0], bufA);
    convm_k<16, 16, true,  9><<<g512, blk, 0, stream>>>(bufA, wp + 3072,  Bv[1], bufB);
    convm_k<16, 32, false, 9><<<g512, blk, 0, stream>>>(bufB, wp + 6144,  Bv[2], du);

    pool_k<<<4096, blk, 0, stream>>>(du, bufA);
    convm_k<32, 32, true, 8><<<g256, blk, 0, stream>>>(bufA, wp + 12288, Bv[3], bufB);
    convm_k<32, 32, true, 8><<<g256, blk, 0, stream>>>(bufB, wp + 21504, Bv[4], bufA);
    convm_k<32, 32, true, 8><<<g256, blk, 0, stream>>>(bufA, wp + 30720, Bv[5], bufB);

    convTm_k<<<g256, blk, 0, stream>>>(bufB, wpT, bt, du);

    convm_k<32, 16, true,  9><<<g512, blk, 0, stream>>>(du,   wp + 39936, Bv[6], bufA);
    convm_k<16, 16, true,  9><<<g512, blk, 0, stream>>>(bufA, wp + 44544, Bv[7], bufB);
    convm_k<16, 16, false, 9><<<g512, blk, 0, stream>>>(bufB, wp + 47616, Bv[8], bufA);

    bil_k<<<g512, blk, 0, stream>>>(x, bufA, fp, out);

    (void)n_in; (void)out_size;
}